// Round 13
// baseline (109.943 us; speedup 1.0000x reference)
//
#include <hip/hip_runtime.h>
#include <hip/hip_bf16.h>
#include <stdint.h>

// Problem constants (fixed by setup_inputs)
#define N_IMG 4
#define A_DIM 256
#define HW    65536            // 256*256 pixels per image
#define C_CLS 19
#define NPIX  (N_IMG*HW)       // 262144
#define CHUNK 512              // pixels per chunk in stats kernel
#define NCHUNK (NPIX/CHUNK)    // 512
#define TSPLIT 16              // first-stage reduction split

// workspace layout (bytes)
#define OFF_LAB  0                      // uint8 labels, 262144 B
#define OFF_S    262144                 // float S05[20][19] = 1520 B
#define OFF_HIST 263680                 // int hists[nblk][20] <= 40960 B
#define OFF_P2   304640                 // float2 p2[16][19][256] = 622592 B
#define OFF_P1   927232                 // float2 partial[nblk][19][256]
#define P1_ROW_BYTES (C_CLS*2*A_DIM*4)  // 38912 B per block row

typedef float natf4 __attribute__((ext_vector_type(4)));   // for nontemporal store

// ---------------- Kernel B: labels + hist + per-class sum & sumsq ----------------
// Thread owns CHANNEL PAIR (2*c2, 2*c2+1); bins row = float4 (s0,q0,s1,q1)
// -> ONE b128 RMW per pixel covers 2 elements (half the LDS-pipe ops of b64).
// Wave-group hf (t>=128) owns pixel half [hf*256, hf*256+256) with its own
// bins copy -> static array split, thread-exclusive columns, deterministic.

__device__ __forceinline__ void load_pair(float4 (&X)[4], float4 (&Y)[4],
                                          const float4* fe4, const float4* fo4, int g) {
#pragma unroll
    for (int k = 0; k < 4; ++k) {
        X[k] = fe4[g * 4 + k];
        Y[k] = fo4[g * 4 + k];
    }
}

__device__ __forceinline__ void acc4pair(float4 X, float4 Y, unsigned w,
                                         float4* __restrict__ bins, int c2) {
#pragma unroll
    for (int i = 0; i < 4; ++i) {
        int lb = (w >> (8 * i)) & 255;    // 0..19, wave-uniform
        float vx = (i == 0) ? X.x : (i == 1) ? X.y : (i == 2) ? X.z : X.w;
        float vy = (i == 0) ? Y.x : (i == 1) ? Y.y : (i == 2) ? Y.z : Y.w;
        bool ok = lb < C_CLS;             // class 19 = ignore
        float v0 = ok ? vx : 0.0f;        // add 0 to row 0 -> harmless
        float v1 = ok ? vy : 0.0f;
        int row = ok ? lb : 0;
        int idx = (row << 7) + c2;        // lane c2: 16B-consecutive -> conflict-free
        float4 x = bins[idx];
        x.x += v0; x.y = fmaf(v0, v0, x.y);
        x.z += v1; x.w = fmaf(v1, v1, x.w);
        bins[idx] = x;
    }
}

__global__ __launch_bounds__(256) void kB_stats(const float* __restrict__ features,
                                                const int* __restrict__ tgt,
                                                uint8_t* __restrict__ lab,
                                                float2* __restrict__ partial,
                                                int* __restrict__ hists, int nblk) {
    __shared__ float4 binsA[C_CLS * 128];     // 38912 B (pixel half 0)
    __shared__ float4 binsB[C_CLS * 128];     // 38912 B (pixel half 1)
    __shared__ unsigned labw[CHUNK / 4];      // 512 B
    __shared__ int hist[20];
    int t = threadIdx.x;
    int hf = t >> 7;                          // pixel-half owner (uniform per wave)
    int c2 = t & 127;                         // channel pair index
    float4* bins = hf ? binsB : binsA;
    for (int i = t; i < C_CLS * 128; i += 256) {
        binsA[i] = make_float4(0.f, 0.f, 0.f, 0.f);
        binsB[i] = make_float4(0.f, 0.f, 0.f, 0.f);
    }
    if (t < 20) hist[t] = 0;

    for (int chk = blockIdx.x; chk < NCHUNK; chk += nblk) {
        int n = chk >> 7;                     // 128 chunks per image
        int p0 = (chk & 127) * CHUNK;
        __syncthreads();                      // init done / prev labw readers done

        // feature loads FIRST (independent of labels) to warm the pipe
        const float* fe = features + (((size_t)(n * A_DIM + 2 * c2)) << 16)
                        + p0 + (hf << 8);
        const float4* fe4 = (const float4*)fe;
        const float4* fo4 = fe4 + (HW / 4);   // adjacent channel (+HW floats)
        float4 XA[4], YA[4], XB[4], YB[4];
        load_pair(XA, YA, fe4, fo4, 0);
        load_pair(XB, YB, fe4, fo4, 1);

        if (t < CHUNK / 4) {
            int p = p0 + t * 4;               // 4 consecutive pixels, same row
            int h = p >> 8, w = p & 255;
            const int* row = tgt + (n << 18) + (h << 10) + (w << 1);
            int4 u0 = *(const int4*)(row);
            int4 u1 = *(const int4*)(row + 4);
            int l0 = (u0.x == 255) ? 19 : u0.x;
            int l1 = (u0.z == 255) ? 19 : u0.z;
            int l2 = (u1.x == 255) ? 19 : u1.x;
            int l3 = (u1.z == 255) ? 19 : u1.z;
            unsigned packed = (unsigned)l0 | ((unsigned)l1 << 8)
                            | ((unsigned)l2 << 16) | ((unsigned)l3 << 24);
            labw[t] = packed;
            ((unsigned*)(lab + n * HW + p0))[t] = packed;   // stage for kD
            atomicAdd(&hist[l0], 1); atomicAdd(&hist[l1], 1);
            atomicAdd(&hist[l2], 1); atomicAdd(&hist[l3], 1);
        }
        __syncthreads();                      // labw ready

#pragma unroll 1
        for (int g = 0; g < 16; g += 2) {     // 16 groups x 16 px = 256 px (half)
#pragma unroll
            for (int k = 0; k < 4; ++k)
                acc4pair(XA[k], YA[k], labw[(hf << 6) + (g << 2) + k], bins, c2);
            if (g + 2 < 16) load_pair(XA, YA, fe4, fo4, g + 2);
#pragma unroll
            for (int k = 0; k < 4; ++k)
                acc4pair(XB[k], YB[k], labw[(hf << 6) + ((g + 1) << 2) + k], bins, c2);
            if (g + 3 < 16) load_pair(XB, YB, fe4, fo4, g + 3);
        }
    }
    __syncthreads();
    // merge pixel-half copies; write classes 0..18 in the SAME partial layout
    float2* dst = partial + (size_t)blockIdx.x * (C_CLS * A_DIM);
    for (int i = t; i < C_CLS * 128; i += 256) {
        int row = i >> 7, cc = i & 127;
        float4 a = binsA[i], b = binsB[i];
        dst[row * A_DIM + 2 * cc]     = make_float2(a.x + b.x, a.y + b.y);
        dst[row * A_DIM + 2 * cc + 1] = make_float2(a.z + b.z, a.w + b.w);
    }
    if (t < 20) hists[blockIdx.x * 20 + t] = hist[t];
}

// ---------------- Kernel C1a: first-stage partial reduction ----------------
__global__ __launch_bounds__(256) void kC1a(const float2* __restrict__ partial,
                                            float2* __restrict__ p2, int nblk) {
    int c = blockIdx.x;            // 0..18
    int s = blockIdx.y;            // 0..15
    int a = threadIdx.x;
    int per = nblk / TSPLIT;
    float sum = 0.f, sq = 0.f;
    for (int b = s * per; b < (s + 1) * per; ++b) {
        float2 v = partial[(size_t)b * (C_CLS * A_DIM) + c * A_DIM + a];
        sum += v.x; sq += v.y;
    }
    p2[(s * C_CLS + c) * A_DIM + a] = make_float2(sum, sq);
}

// ---------------- Kernel CF: finalize CoV (in regs) + S row ----------------
__global__ __launch_bounds__(256) void kCF(const float2* __restrict__ p2,
                                           const int* __restrict__ hists, int nblk,
                                           const float* __restrict__ Amount,
                                           const float* __restrict__ Ave,
                                           const float* __restrict__ CoVin,
                                           const float* __restrict__ W,
                                           const float* __restrict__ ratio,
                                           float* __restrict__ S) {
    int k = blockIdx.x, t = threadIdx.x;
    if (k == 19) {                 // ignore-row: sigma2 contribution is zero
        if (t < C_CLS) S[19 * C_CLS + t] = 0.0f;
        return;
    }
    __shared__ float sred[4];
    __shared__ float red[C_CLS][4];
    int lane = t & 63, wv = t >> 6;
    int csum = 0;
    for (int b = t; b < nblk; b += 256) csum += hists[b * 20 + k];
#pragma unroll
    for (int o = 32; o > 0; o >>= 1) csum += __shfl_xor(csum, o, 64);
    if (lane == 0) sred[wv] = (float)csum;
    __syncthreads();
    float cnt = sred[0] + sred[1] + sred[2] + sred[3];

    float sum = 0.f, sq = 0.f;
#pragma unroll
    for (int s = 0; s < TSPLIT; ++s) {
        float2 v = p2[(s * C_CLS + k) * A_DIM + t];
        sum += v.x; sq += v.y;
    }
    float denom = fmaxf(cnt, 1.0f);
    float ave = sum / denom;
    float var = (sq - 2.0f * ave * sum + ave * ave * cnt) / denom;
    float dw = cnt + Amount[k];
    float w = (dw != 0.0f) ? (cnt / dw) : 0.0f;   // nan(0/0) -> 0 rule
    float d = Ave[k * A_DIM + t] - ave;
    float cv = CoVin[k * A_DIM + t] * (1.0f - w) + var * w + w * (1.0f - w) * d * d;

    float wk = W[k * A_DIM + t];
    for (int c = 0; c < C_CLS; ++c) {
        float dd = W[c * A_DIM + t] - wk;
        float term = dd * dd * cv;
#pragma unroll
        for (int o = 32; o > 0; o >>= 1) term += __shfl_xor(term, o, 64);
        if (lane == 0) red[c][wv] = term;
    }
    __syncthreads();
    if (t < C_CLS)
        S[k * C_CLS + t] = 0.5f * ratio[0] * (red[t][0] + red[t][1] + red[t][2] + red[t][3]);
}

// ---------------- Kernel D: out = y + S05[lab][c] ----------------
__global__ __launch_bounds__(256) void kD_apply(const float* __restrict__ y,
                                                const uint8_t* __restrict__ lab,
                                                const float* __restrict__ S,
                                                float* __restrict__ out) {
    __shared__ float sS[20 * C_CLS];
    int t = threadIdx.x;
    for (int i = t; i < 20 * C_CLS; i += 256) sS[i] = S[i];
    __syncthreads();
    int idx4 = blockIdx.x * 256 + t;          // float4 index
    int plane = idx4 >> 14;                   // (n*19 + c); 16384 float4 per plane
    int p4 = idx4 & 16383;
    int n = plane / C_CLS;
    int c = plane - n * C_CLS;
    float4 yv = ((const float4*)y)[idx4];
    unsigned lw = *(((const unsigned*)(lab + n * HW)) + p4);
    natf4 o;
    o.x = yv.x + sS[((lw      ) & 255) * C_CLS + c];
    o.y = yv.y + sS[((lw >> 8 ) & 255) * C_CLS + c];
    o.z = yv.z + sS[((lw >> 16) & 255) * C_CLS + c];
    o.w = yv.w + sS[((lw >> 24)      ) * C_CLS + c];
    // nontemporal: out is never re-read -> keep L3 slots for features
    __builtin_nontemporal_store(o, (natf4*)out + idx4);
}

// ---------------- launcher ----------------
extern "C" void kernel_launch(void* const* d_in, const int* in_sizes, int n_in,
                              void* d_out, int out_size, void* d_ws, size_t ws_size,
                              hipStream_t stream) {
    const float* features  = (const float*)d_in[0];
    const float* fc_weight = (const float*)d_in[1];
    const float* y         = (const float*)d_in[2];
    const float* Ave       = (const float*)d_in[3];
    const float* CoVin     = (const float*)d_in[4];
    const float* Amount    = (const float*)d_in[5];
    const float* ratio     = (const float*)d_in[6];
    const int*   target_x  = (const int*)d_in[7];
    float* out             = (float*)d_out;

    char* ws = (char*)d_ws;
    uint8_t* lab    = (uint8_t*)(ws + OFF_LAB);
    float*   S      = (float*)(ws + OFF_S);
    int*     hists  = (int*)(ws + OFF_HIST);
    float2*  p2     = (float2*)(ws + OFF_P2);
    float2*  partial= (float2*)(ws + OFF_P1);

    size_t avail = (ws_size > (size_t)OFF_P1) ? (ws_size - OFF_P1) : 0;
    int nblk = (int)(avail / P1_ROW_BYTES);
    if (nblk > 512) nblk = 512;
    nblk &= ~15;                 // multiple of TSPLIT
    if (nblk < 16) nblk = 16;    // minimal fallback

    kB_stats<<<nblk, 256, 0, stream>>>(features, target_x, lab, partial, hists, nblk);
    kC1a<<<dim3(C_CLS, TSPLIT), 256, 0, stream>>>(partial, p2, nblk);
    kCF<<<20, 256, 0, stream>>>(p2, hists, nblk, Amount, Ave, CoVin, fc_weight, ratio, S);
    kD_apply<<<(NPIX * C_CLS / 4) / 256, 256, 0, stream>>>(y, lab, S, out);
}

// Round 14
// 83.476 us; speedup vs baseline: 1.3171x; 1.3171x over previous
//
#include <hip/hip_runtime.h>
#include <hip/hip_bf16.h>
#include <stdint.h>

// Problem constants (fixed by setup_inputs)
#define N_IMG 4
#define A_DIM 256
#define HW    65536            // 256*256 pixels per image
#define C_CLS 19
#define NPIX  (N_IMG*HW)       // 262144
#define CHUNK 512              // pixels per chunk in stats kernel
#define NCHUNK (NPIX/CHUNK)    // 512
#define TSPLIT 16              // first-stage reduction split

// workspace layout (bytes)
#define OFF_LAB  0                      // uint8 labels, 262144 B
#define OFF_S    262144                 // float S05[20][19] = 1520 B
#define OFF_HIST 263680                 // int hists[nblk][20] <= 40960 B
#define OFF_P2   304640                 // float2 p2[16][19][256] = 622592 B
#define OFF_P1   927232                 // float2 partial[nblk][19][256]
#define P1_ROW_BYTES (C_CLS*2*A_DIM*4)  // 38912 B per block row

typedef float natf4 __attribute__((ext_vector_type(4)));   // for nontemporal store

// ---------------- Kernel B: labels + hist + per-class sum & sumsq ----------------

// swap adjacent lanes (2i <-> 2i+1) via DPP quad_perm(1,0,3,2) - pure VALU
__device__ __forceinline__ float4 dpp_swap_f4(float4 v) {
    union { float4 f; int i[4]; } a, r;
    a.f = v;
#pragma unroll
    for (int k = 0; k < 4; ++k)
        r.i[k] = __builtin_amdgcn_update_dpp(0, a.i[k], 0xB1, 0xF, 0xF, true);
    return r.f;
}

// Plain LDS RMW, float2 b64 (champion structure). Column t of each array is
// touched ONLY by thread t; even/odd pixels use separate copies -> 2 chains.
__device__ __forceinline__ void acc4(float4 vv, unsigned w,
                                     float2* __restrict__ b0,
                                     float2* __restrict__ b1, int t) {
#pragma unroll
    for (int i = 0; i < 4; ++i) {
        int lb = (w >> (8 * i)) & 255;    // 0..19
        float v = (i == 0) ? vv.x : (i == 1) ? vv.y : (i == 2) ? vv.z : vv.w;
        bool ok = lb < C_CLS;             // class 19 = ignore
        float vm = ok ? v : 0.0f;         // add 0 to row 0 -> harmless
        int row = ok ? lb : 0;
        int idx = (row << 8) + t;
        if (i & 1) {
            float2 x = b1[idx]; x.x += vm; x.y = fmaf(vm, vm, x.y); b1[idx] = x;
        } else {
            float2 x = b0[idx]; x.x += vm; x.y = fmaf(vm, vm, x.y); b0[idx] = x;
        }
    }
}

// load one group: 4 pair-steps (j = 4g..4g+3), X from even channel, Y from odd.
__device__ __forceinline__ void load_pair(float4 (&X)[4], float4 (&Y)[4],
                                          const float* fe, const float* fo, int g) {
#pragma unroll
    for (int jj = 0; jj < 4; ++jj) {
        X[jj] = *(const float4*)(fe + 8 * (4 * g + jj));
        Y[jj] = *(const float4*)(fo + 8 * (4 * g + jj));
    }
}

__device__ __forceinline__ void proc_pair(const float4 (&X)[4], const float4 (&Y)[4],
                                          int g, bool podd, const unsigned* lw,
                                          float2* __restrict__ b0,
                                          float2* __restrict__ b1, int t) {
#pragma unroll
    for (int jj = 0; jj < 4; ++jj) {
        int j = 4 * g + jj;
        float4 send = podd ? X[jj] : Y[jj];
        float4 recv = dpp_swap_f4(send);
        float4 lo = podd ? recv : X[jj];  // (ch t, px 8j+0..3)
        float4 hi = podd ? Y[jj] : recv;  // (ch t, px 8j+4..7)
        acc4(lo, lw[2 * j],     b0, b1, t);
        acc4(hi, lw[2 * j + 1], b0, b1, t);
    }
}

__global__ __launch_bounds__(256) void kB_stats(const float* __restrict__ features,
                                                const int* __restrict__ tgt,
                                                uint8_t* __restrict__ lab,
                                                float2* __restrict__ partial,
                                                int* __restrict__ hists, int nblk) {
    __shared__ float2 bins0[C_CLS * A_DIM];   // 38912 B each; 2 copies = 77824 B
    __shared__ float2 bins1[C_CLS * A_DIM];   // -> 2 blocks/CU
    __shared__ unsigned labw[CHUNK / 4];      // 512 B
    __shared__ int hist[20];
    int t = threadIdx.x;
    bool podd = (t & 1);
    for (int i = t; i < C_CLS * A_DIM; i += 256) {
        bins0[i] = make_float2(0.f, 0.f);
        bins1[i] = make_float2(0.f, 0.f);
    }
    if (t < 20) hist[t] = 0;

    for (int chk = blockIdx.x; chk < NCHUNK; chk += nblk) {
        int n = chk >> 7;                     // 128 chunks per image
        int p0 = (chk & 127) * CHUNK;
        __syncthreads();                      // init done / prev labw readers done

        // paired coalesced bases: lane pair (2i,2i+1) reads adjacent 16B
        const float* fbase = features + (((size_t)n * A_DIM) << 16) + p0 + 4 * (t & 1);
        const float* fe = fbase + ((size_t)(t & ~1) << 16);   // even channel
        const float* fo = fbase + ((size_t)(t |  1) << 16);   // odd channel

        float4 XA[4], YA[4], XB[4], YB[4];
        load_pair(XA, YA, fe, fo, 0);         // warm the pipe before label phase
        load_pair(XB, YB, fe, fo, 1);

        if (t < CHUNK / 4) {
            int p = p0 + t * 4;               // 4 consecutive pixels, same row
            int h = p >> 8, w = p & 255;
            const int* row = tgt + (n << 18) + (h << 10) + (w << 1);
            int4 u0 = *(const int4*)(row);
            int4 u1 = *(const int4*)(row + 4);
            int l0 = (u0.x == 255) ? 19 : u0.x;
            int l1 = (u0.z == 255) ? 19 : u0.z;
            int l2 = (u1.x == 255) ? 19 : u1.x;
            int l3 = (u1.z == 255) ? 19 : u1.z;
            unsigned packed = (unsigned)l0 | ((unsigned)l1 << 8)
                            | ((unsigned)l2 << 16) | ((unsigned)l3 << 24);
            labw[t] = packed;
            ((unsigned*)(lab + n * HW + p0))[t] = packed;   // stage for kD
            atomicAdd(&hist[l0], 1); atomicAdd(&hist[l1], 1);
            atomicAdd(&hist[l2], 1); atomicAdd(&hist[l3], 1);
        }
        __syncthreads();                      // labw ready

#pragma unroll 1
        for (int g = 0; g < 16; g += 2) {
            proc_pair(XA, YA, g, podd, labw, bins0, bins1, t);
            if (g + 2 < 16) load_pair(XA, YA, fe, fo, g + 2);
            proc_pair(XB, YB, g + 1, podd, labw, bins0, bins1, t);
            if (g + 3 < 16) load_pair(XB, YB, fe, fo, g + 3);
        }
    }
    __syncthreads();
    // merge even/odd copies, write classes 0..18
    float2* dst = partial + (size_t)blockIdx.x * (C_CLS * A_DIM);
    for (int i = t; i < C_CLS * A_DIM; i += 256)
        dst[i] = make_float2(bins0[i].x + bins1[i].x, bins0[i].y + bins1[i].y);
    if (t < 20) hists[blockIdx.x * 20 + t] = hist[t];
}

// ---------------- Kernel C1a: first-stage partial reduction ----------------
__global__ __launch_bounds__(256) void kC1a(const float2* __restrict__ partial,
                                            float2* __restrict__ p2, int nblk) {
    int c = blockIdx.x;            // 0..18
    int s = blockIdx.y;            // 0..15
    int a = threadIdx.x;
    int per = nblk / TSPLIT;
    float sum = 0.f, sq = 0.f;
    for (int b = s * per; b < (s + 1) * per; ++b) {
        float2 v = partial[(size_t)b * (C_CLS * A_DIM) + c * A_DIM + a];
        sum += v.x; sq += v.y;
    }
    p2[(s * C_CLS + c) * A_DIM + a] = make_float2(sum, sq);
}

// ---------------- Kernel CF: finalize CoV (in regs) + S row ----------------
__global__ __launch_bounds__(256) void kCF(const float2* __restrict__ p2,
                                           const int* __restrict__ hists, int nblk,
                                           const float* __restrict__ Amount,
                                           const float* __restrict__ Ave,
                                           const float* __restrict__ CoVin,
                                           const float* __restrict__ W,
                                           const float* __restrict__ ratio,
                                           float* __restrict__ S) {
    int k = blockIdx.x, t = threadIdx.x;
    if (k == 19) {                 // ignore-row: sigma2 contribution is zero
        if (t < C_CLS) S[19 * C_CLS + t] = 0.0f;
        return;
    }
    __shared__ float sred[4];
    __shared__ float red[C_CLS][4];
    int lane = t & 63, wv = t >> 6;
    int csum = 0;
    for (int b = t; b < nblk; b += 256) csum += hists[b * 20 + k];
#pragma unroll
    for (int o = 32; o > 0; o >>= 1) csum += __shfl_xor(csum, o, 64);
    if (lane == 0) sred[wv] = (float)csum;
    __syncthreads();
    float cnt = sred[0] + sred[1] + sred[2] + sred[3];

    float sum = 0.f, sq = 0.f;
#pragma unroll
    for (int s = 0; s < TSPLIT; ++s) {
        float2 v = p2[(s * C_CLS + k) * A_DIM + t];
        sum += v.x; sq += v.y;
    }
    float denom = fmaxf(cnt, 1.0f);
    float ave = sum / denom;
    float var = (sq - 2.0f * ave * sum + ave * ave * cnt) / denom;
    float dw = cnt + Amount[k];
    float w = (dw != 0.0f) ? (cnt / dw) : 0.0f;   // nan(0/0) -> 0 rule
    float d = Ave[k * A_DIM + t] - ave;
    float cv = CoVin[k * A_DIM + t] * (1.0f - w) + var * w + w * (1.0f - w) * d * d;

    float wk = W[k * A_DIM + t];
    for (int c = 0; c < C_CLS; ++c) {
        float dd = W[c * A_DIM + t] - wk;
        float term = dd * dd * cv;
#pragma unroll
        for (int o = 32; o > 0; o >>= 1) term += __shfl_xor(term, o, 64);
        if (lane == 0) red[c][wv] = term;
    }
    __syncthreads();
    if (t < C_CLS)
        S[k * C_CLS + t] = 0.5f * ratio[0] * (red[t][0] + red[t][1] + red[t][2] + red[t][3]);
}

// ---------------- Kernel D: out = y + S05[lab][c] ----------------
__global__ __launch_bounds__(256) void kD_apply(const float* __restrict__ y,
                                                const uint8_t* __restrict__ lab,
                                                const float* __restrict__ S,
                                                float* __restrict__ out) {
    __shared__ float sS[20 * C_CLS];
    int t = threadIdx.x;
    for (int i = t; i < 20 * C_CLS; i += 256) sS[i] = S[i];
    __syncthreads();
    int idx4 = blockIdx.x * 256 + t;          // float4 index
    int plane = idx4 >> 14;                   // (n*19 + c); 16384 float4 per plane
    int p4 = idx4 & 16383;
    int n = plane / C_CLS;
    int c = plane - n * C_CLS;
    float4 yv = ((const float4*)y)[idx4];
    unsigned lw = *(((const unsigned*)(lab + n * HW)) + p4);
    natf4 o;
    o.x = yv.x + sS[((lw      ) & 255) * C_CLS + c];
    o.y = yv.y + sS[((lw >> 8 ) & 255) * C_CLS + c];
    o.z = yv.z + sS[((lw >> 16) & 255) * C_CLS + c];
    o.w = yv.w + sS[((lw >> 24)      ) * C_CLS + c];
    // nontemporal: out is never re-read -> keep L3 slots for features
    __builtin_nontemporal_store(o, (natf4*)out + idx4);
}

// ---------------- launcher ----------------
extern "C" void kernel_launch(void* const* d_in, const int* in_sizes, int n_in,
                              void* d_out, int out_size, void* d_ws, size_t ws_size,
                              hipStream_t stream) {
    const float* features  = (const float*)d_in[0];
    const float* fc_weight = (const float*)d_in[1];
    const float* y         = (const float*)d_in[2];
    const float* Ave       = (const float*)d_in[3];
    const float* CoVin     = (const float*)d_in[4];
    const float* Amount    = (const float*)d_in[5];
    const float* ratio     = (const float*)d_in[6];
    const int*   target_x  = (const int*)d_in[7];
    float* out             = (float*)d_out;

    char* ws = (char*)d_ws;
    uint8_t* lab    = (uint8_t*)(ws + OFF_LAB);
    float*   S      = (float*)(ws + OFF_S);
    int*     hists  = (int*)(ws + OFF_HIST);
    float2*  p2     = (float2*)(ws + OFF_P2);
    float2*  partial= (float2*)(ws + OFF_P1);

    size_t avail = (ws_size > (size_t)OFF_P1) ? (ws_size - OFF_P1) : 0;
    int nblk = (int)(avail / P1_ROW_BYTES);
    if (nblk > 512) nblk = 512;
    nblk &= ~15;                 // multiple of TSPLIT
    if (nblk < 16) nblk = 16;    // minimal fallback

    kB_stats<<<nblk, 256, 0, stream>>>(features, target_x, lab, partial, hists, nblk);
    kC1a<<<dim3(C_CLS, TSPLIT), 256, 0, stream>>>(partial, p2, nblk);
    kCF<<<20, 256, 0, stream>>>(p2, hists, nblk, Amount, Ave, CoVin, fc_weight, ratio, S);
    kD_apply<<<(NPIX * C_CLS / 4) / 256, 256, 0, stream>>>(y, lab, S, out);
}

// Round 15
// 82.416 us; speedup vs baseline: 1.3340x; 1.0129x over previous
//
#include <hip/hip_runtime.h>
#include <hip/hip_bf16.h>
#include <stdint.h>

// Problem constants (fixed by setup_inputs)
#define N_IMG 4
#define A_DIM 256
#define HW    65536            // 256*256 pixels per image
#define C_CLS 19
#define NPIX  (N_IMG*HW)       // 262144
#define CHUNK 512              // pixels per chunk in stats kernel
#define NCHUNK (NPIX/CHUNK)    // 512
#define TSPLIT 16              // first-stage reduction split

// workspace layout (bytes)
#define OFF_LAB  0                      // uint8 labels, 262144 B
#define OFF_S    262144                 // float S05[20][19] = 1520 B
#define OFF_HIST 263680                 // int hists[nblk][20] <= 40960 B
#define OFF_P2   304640                 // float2 p2[16][19][256] = 622592 B
#define OFF_P1   927232                 // float2 partial[nblk][19][256]
#define P1_ROW_BYTES (C_CLS*2*A_DIM*4)  // 38912 B per block row

typedef float natf4 __attribute__((ext_vector_type(4)));   // for nontemporal ld/st

// ---------------- Kernel B: labels + hist + per-class sum & sumsq ----------------

// swap adjacent lanes (2i <-> 2i+1) via DPP quad_perm(1,0,3,2) - pure VALU
__device__ __forceinline__ float4 dpp_swap_f4(float4 v) {
    union { float4 f; int i[4]; } a, r;
    a.f = v;
#pragma unroll
    for (int k = 0; k < 4; ++k)
        r.i[k] = __builtin_amdgcn_update_dpp(0, a.i[k], 0xB1, 0xF, 0xF, true);
    return r.f;
}

// Plain LDS RMW, float2 b64 (champion structure). Column t of each array is
// touched ONLY by thread t; even/odd pixels use separate copies -> 2 chains.
__device__ __forceinline__ void acc4(float4 vv, unsigned w,
                                     float2* __restrict__ b0,
                                     float2* __restrict__ b1, int t) {
#pragma unroll
    for (int i = 0; i < 4; ++i) {
        int lb = (w >> (8 * i)) & 255;    // 0..19
        float v = (i == 0) ? vv.x : (i == 1) ? vv.y : (i == 2) ? vv.z : vv.w;
        bool ok = lb < C_CLS;             // class 19 = ignore
        float vm = ok ? v : 0.0f;         // add 0 to row 0 -> harmless
        int row = ok ? lb : 0;
        int idx = (row << 8) + t;
        if (i & 1) {
            float2 x = b1[idx]; x.x += vm; x.y = fmaf(vm, vm, x.y); b1[idx] = x;
        } else {
            float2 x = b0[idx]; x.x += vm; x.y = fmaf(vm, vm, x.y); b0[idx] = x;
        }
    }
}

// load one group: 4 pair-steps (j = 4g..4g+3), X from even channel, Y from odd.
__device__ __forceinline__ void load_pair(float4 (&X)[4], float4 (&Y)[4],
                                          const float* fe, const float* fo, int g) {
#pragma unroll
    for (int jj = 0; jj < 4; ++jj) {
        X[jj] = *(const float4*)(fe + 8 * (4 * g + jj));
        Y[jj] = *(const float4*)(fo + 8 * (4 * g + jj));
    }
}

__device__ __forceinline__ void proc_pair(const float4 (&X)[4], const float4 (&Y)[4],
                                          int g, bool podd, const unsigned* lw,
                                          float2* __restrict__ b0,
                                          float2* __restrict__ b1, int t) {
#pragma unroll
    for (int jj = 0; jj < 4; ++jj) {
        int j = 4 * g + jj;
        float4 send = podd ? X[jj] : Y[jj];
        float4 recv = dpp_swap_f4(send);
        float4 lo = podd ? recv : X[jj];  // (ch t, px 8j+0..3)
        float4 hi = podd ? Y[jj] : recv;  // (ch t, px 8j+4..7)
        acc4(lo, lw[2 * j],     b0, b1, t);
        acc4(hi, lw[2 * j + 1], b0, b1, t);
    }
}

__global__ __launch_bounds__(256) void kB_stats(const float* __restrict__ features,
                                                const int* __restrict__ tgt,
                                                uint8_t* __restrict__ lab,
                                                float2* __restrict__ partial,
                                                int* __restrict__ hists, int nblk) {
    __shared__ float2 bins0[C_CLS * A_DIM];   // 38912 B each; 2 copies = 77824 B
    __shared__ float2 bins1[C_CLS * A_DIM];   // -> 2 blocks/CU
    __shared__ unsigned labw[CHUNK / 4];      // 512 B
    __shared__ int hist[20];
    int t = threadIdx.x;
    bool podd = (t & 1);
    for (int i = t; i < C_CLS * A_DIM; i += 256) {
        bins0[i] = make_float2(0.f, 0.f);
        bins1[i] = make_float2(0.f, 0.f);
    }
    if (t < 20) hist[t] = 0;

    for (int chk = blockIdx.x; chk < NCHUNK; chk += nblk) {
        int n = chk >> 7;                     // 128 chunks per image
        int p0 = (chk & 127) * CHUNK;
        __syncthreads();                      // init done / prev labw readers done

        // paired coalesced bases: lane pair (2i,2i+1) reads adjacent 16B
        const float* fbase = features + (((size_t)n * A_DIM) << 16) + p0 + 4 * (t & 1);
        const float* fe = fbase + ((size_t)(t & ~1) << 16);   // even channel
        const float* fo = fbase + ((size_t)(t |  1) << 16);   // odd channel

        float4 XA[4], YA[4], XB[4], YB[4];
        load_pair(XA, YA, fe, fo, 0);         // warm the pipe before label phase
        load_pair(XB, YB, fe, fo, 1);

        if (t < CHUNK / 4) {
            int p = p0 + t * 4;               // 4 consecutive pixels, same row
            int h = p >> 8, w = p & 255;
            const int* row = tgt + (n << 18) + (h << 10) + (w << 1);
            int4 u0 = *(const int4*)(row);
            int4 u1 = *(const int4*)(row + 4);
            int l0 = (u0.x == 255) ? 19 : u0.x;
            int l1 = (u0.z == 255) ? 19 : u0.z;
            int l2 = (u1.x == 255) ? 19 : u1.x;
            int l3 = (u1.z == 255) ? 19 : u1.z;
            unsigned packed = (unsigned)l0 | ((unsigned)l1 << 8)
                            | ((unsigned)l2 << 16) | ((unsigned)l3 << 24);
            labw[t] = packed;
            ((unsigned*)(lab + n * HW + p0))[t] = packed;   // stage for kD
            atomicAdd(&hist[l0], 1); atomicAdd(&hist[l1], 1);
            atomicAdd(&hist[l2], 1); atomicAdd(&hist[l3], 1);
        }
        __syncthreads();                      // labw ready

#pragma unroll 1
        for (int g = 0; g < 16; g += 2) {
            proc_pair(XA, YA, g, podd, labw, bins0, bins1, t);
            if (g + 2 < 16) load_pair(XA, YA, fe, fo, g + 2);
            proc_pair(XB, YB, g + 1, podd, labw, bins0, bins1, t);
            if (g + 3 < 16) load_pair(XB, YB, fe, fo, g + 3);
        }
    }
    __syncthreads();
    // merge even/odd copies, write classes 0..18
    float2* dst = partial + (size_t)blockIdx.x * (C_CLS * A_DIM);
    for (int i = t; i < C_CLS * A_DIM; i += 256)
        dst[i] = make_float2(bins0[i].x + bins1[i].x, bins0[i].y + bins1[i].y);
    if (t < 20) hists[blockIdx.x * 20 + t] = hist[t];
}

// ---------------- Kernel C1a: first-stage partial reduction ----------------
__global__ __launch_bounds__(256) void kC1a(const float2* __restrict__ partial,
                                            float2* __restrict__ p2, int nblk) {
    int c = blockIdx.x;            // 0..18
    int s = blockIdx.y;            // 0..15
    int a = threadIdx.x;
    int per = nblk / TSPLIT;
    float sum = 0.f, sq = 0.f;
    for (int b = s * per; b < (s + 1) * per; ++b) {
        float2 v = partial[(size_t)b * (C_CLS * A_DIM) + c * A_DIM + a];
        sum += v.x; sq += v.y;
    }
    p2[(s * C_CLS + c) * A_DIM + a] = make_float2(sum, sq);
}

// ---------------- Kernel CF: finalize CoV (in regs) + S row ----------------
__global__ __launch_bounds__(256) void kCF(const float2* __restrict__ p2,
                                           const int* __restrict__ hists, int nblk,
                                           const float* __restrict__ Amount,
                                           const float* __restrict__ Ave,
                                           const float* __restrict__ CoVin,
                                           const float* __restrict__ W,
                                           const float* __restrict__ ratio,
                                           float* __restrict__ S) {
    int k = blockIdx.x, t = threadIdx.x;
    if (k == 19) {                 // ignore-row: sigma2 contribution is zero
        if (t < C_CLS) S[19 * C_CLS + t] = 0.0f;
        return;
    }
    __shared__ float sred[4];
    __shared__ float red[C_CLS][4];
    int lane = t & 63, wv = t >> 6;
    int csum = 0;
    for (int b = t; b < nblk; b += 256) csum += hists[b * 20 + k];
#pragma unroll
    for (int o = 32; o > 0; o >>= 1) csum += __shfl_xor(csum, o, 64);
    if (lane == 0) sred[wv] = (float)csum;
    __syncthreads();
    float cnt = sred[0] + sred[1] + sred[2] + sred[3];

    float sum = 0.f, sq = 0.f;
#pragma unroll
    for (int s = 0; s < TSPLIT; ++s) {
        float2 v = p2[(s * C_CLS + k) * A_DIM + t];
        sum += v.x; sq += v.y;
    }
    float denom = fmaxf(cnt, 1.0f);
    float ave = sum / denom;
    float var = (sq - 2.0f * ave * sum + ave * ave * cnt) / denom;
    float dw = cnt + Amount[k];
    float w = (dw != 0.0f) ? (cnt / dw) : 0.0f;   // nan(0/0) -> 0 rule
    float d = Ave[k * A_DIM + t] - ave;
    float cv = CoVin[k * A_DIM + t] * (1.0f - w) + var * w + w * (1.0f - w) * d * d;

    float wk = W[k * A_DIM + t];
    for (int c = 0; c < C_CLS; ++c) {
        float dd = W[c * A_DIM + t] - wk;
        float term = dd * dd * cv;
#pragma unroll
        for (int o = 32; o > 0; o >>= 1) term += __shfl_xor(term, o, 64);
        if (lane == 0) red[c][wv] = term;
    }
    __syncthreads();
    if (t < C_CLS)
        S[k * C_CLS + t] = 0.5f * ratio[0] * (red[t][0] + red[t][1] + red[t][2] + red[t][3]);
}

// ---------------- Kernel D: out = y + S05[lab][c] ----------------
__global__ __launch_bounds__(256) void kD_apply(const float* __restrict__ y,
                                                const uint8_t* __restrict__ lab,
                                                const float* __restrict__ S,
                                                float* __restrict__ out) {
    __shared__ float sS[20 * C_CLS];
    int t = threadIdx.x;
    for (int i = t; i < 20 * C_CLS; i += 256) sS[i] = S[i];
    __syncthreads();
    int idx4 = blockIdx.x * 256 + t;          // float4 index
    int plane = idx4 >> 14;                   // (n*19 + c); 16384 float4 per plane
    int p4 = idx4 & 16383;
    int n = plane / C_CLS;
    int c = plane - n * C_CLS;
    // nontemporal: y is read exactly once -> don't displace features in L3
    natf4 yv = __builtin_nontemporal_load((const natf4*)y + idx4);
    unsigned lw = *(((const unsigned*)(lab + n * HW)) + p4);
    natf4 o;
    o.x = yv.x + sS[((lw      ) & 255) * C_CLS + c];
    o.y = yv.y + sS[((lw >> 8 ) & 255) * C_CLS + c];
    o.z = yv.z + sS[((lw >> 16) & 255) * C_CLS + c];
    o.w = yv.w + sS[((lw >> 24)      ) * C_CLS + c];
    // nontemporal: out is never re-read -> keep L3 slots for features
    __builtin_nontemporal_store(o, (natf4*)out + idx4);
}

// ---------------- launcher ----------------
extern "C" void kernel_launch(void* const* d_in, const int* in_sizes, int n_in,
                              void* d_out, int out_size, void* d_ws, size_t ws_size,
                              hipStream_t stream) {
    const float* features  = (const float*)d_in[0];
    const float* fc_weight = (const float*)d_in[1];
    const float* y         = (const float*)d_in[2];
    const float* Ave       = (const float*)d_in[3];
    const float* CoVin     = (const float*)d_in[4];
    const float* Amount    = (const float*)d_in[5];
    const float* ratio     = (const float*)d_in[6];
    const int*   target_x  = (const int*)d_in[7];
    float* out             = (float*)d_out;

    char* ws = (char*)d_ws;
    uint8_t* lab    = (uint8_t*)(ws + OFF_LAB);
    float*   S      = (float*)(ws + OFF_S);
    int*     hists  = (int*)(ws + OFF_HIST);
    float2*  p2     = (float2*)(ws + OFF_P2);
    float2*  partial= (float2*)(ws + OFF_P1);

    size_t avail = (ws_size > (size_t)OFF_P1) ? (ws_size - OFF_P1) : 0;
    int nblk = (int)(avail / P1_ROW_BYTES);
    if (nblk > 512) nblk = 512;
    nblk &= ~15;                 // multiple of TSPLIT
    if (nblk < 16) nblk = 16;    // minimal fallback

    kB_stats<<<nblk, 256, 0, stream>>>(features, target_x, lab, partial, hists, nblk);
    kC1a<<<dim3(C_CLS, TSPLIT), 256, 0, stream>>>(partial, p2, nblk);
    kCF<<<20, 256, 0, stream>>>(p2, hists, nblk, Amount, Ave, CoVin, fc_weight, ratio, S);
    kD_apply<<<(NPIX * C_CLS / 4) / 256, 256, 0, stream>>>(y, lab, S, out);
}